// Round 15
// baseline (126.168 us; speedup 1.0000x reference)
//
#include <hip/hip_runtime.h>
#include <hip/hip_bf16.h>

typedef unsigned short u16;
typedef unsigned int u32;
typedef __attribute__((ext_vector_type(8))) short bf16x8;
typedef __attribute__((ext_vector_type(4))) float f32x4;

#define NN 2048
#define DM 256
#define ED 16
#define HH 8
#define QK 32
#define VV 32
#define OUTD 256

// LDS-only barrier: drain LDS ops, then barrier, WITHOUT draining vmcnt.
#define LBAR() asm volatile("s_waitcnt lgkmcnt(0)\n\ts_barrier" ::: "memory")

// ---------- helpers ----------
__device__ __forceinline__ float fexp2(float x) { return __builtin_amdgcn_exp2f(x); }
__device__ __forceinline__ u16 f2bf(float f) {
    __hip_bfloat16 h = __float2bfloat16(f);
    return *reinterpret_cast<u16*>(&h);
}
__device__ __forceinline__ u32 cvt2(float a, float b) {
    __hip_bfloat162 h = __float22bfloat162_rn(make_float2(a, b));
    return *reinterpret_cast<u32*>(&h);
}

// ---------- K1: projections (weights staged through LDS) ----------
// grid 512 = 8 h * 64 n-tiles(32 rows), 256 thr
// Scale includes log2(e): logits come out in log2 domain (k2/k3 use exp2).
__global__ __launch_bounds__(256) void k1_precompute(
    const float* __restrict__ node_g, const float* __restrict__ qt_g,
    const float* __restrict__ nkt_g, const float* __restrict__ nvt_g,
    const float* __restrict__ ek_g,
    u16* __restrict__ qbf, u16* __restrict__ qebf,
    u16* __restrict__ nk_ws, u16* __restrict__ nvT_ws) {
    __shared__ __align__(16) float node_s[32][256];   // 32 KB
    __shared__ __align__(16) float qtmp_s[32][32];    // 4 KB
    __shared__ __align__(16) float w_s2[256 * 32];    // 32 KB (one weight matrix)
    const int t = threadIdx.x;
    const int h = blockIdx.x >> 6;
    const int n0 = (blockIdx.x & 63) * 32;
    // stage node rows (32 x 256 f32) + first weight (qt)
#pragma unroll
    for (int c = 0; c < 8; ++c) {
        const int ci = t + c * 256;
        const int nl = ci >> 6, d4 = ci & 63;
        *(float4*)&node_s[nl][d4 * 4] =
            *(const float4*)&node_g[(size_t)(n0 + nl) * 256 + d4 * 4];
    }
#pragma unroll
    for (int c = 0; c < 8; ++c)
        *(float4*)&w_s2[t * 4 + c * 1024] =
            *(const float4*)&qt_g[(size_t)h * (DM * QK) + t * 4 + c * 1024];
    __syncthreads();
    const int q = t & 31, nb = t >> 5;
    const float scale = 0.17677669529663689f * 1.4426950408889634f; // (1/sqrt32)*log2e

// PROJ reads the staged weight from LDS: thread q reads column q (bank q, broadcast across nb)
#define PROJ_LOOP(STORE0, STORE1, STORE2, STORE3)                              \
    {                                                                          \
        float a0 = 0.f, a1 = 0.f, a2 = 0.f, a3 = 0.f;                          \
        for (int d4 = 0; d4 < 64; ++d4) {                                      \
            const float w0 = w_s2[(d4 * 4 + 0) * 32 + q];                      \
            const float w1 = w_s2[(d4 * 4 + 1) * 32 + q];                      \
            const float w2 = w_s2[(d4 * 4 + 2) * 32 + q];                      \
            const float w3 = w_s2[(d4 * 4 + 3) * 32 + q];                      \
            float4 nd;                                                         \
            nd = *(const float4*)&node_s[nb][d4 * 4];                          \
            a0 += nd.x * w0 + nd.y * w1 + nd.z * w2 + nd.w * w3;               \
            nd = *(const float4*)&node_s[nb + 8][d4 * 4];                      \
            a1 += nd.x * w0 + nd.y * w1 + nd.z * w2 + nd.w * w3;               \
            nd = *(const float4*)&node_s[nb + 16][d4 * 4];                     \
            a2 += nd.x * w0 + nd.y * w1 + nd.z * w2 + nd.w * w3;               \
            nd = *(const float4*)&node_s[nb + 24][d4 * 4];                     \
            a3 += nd.x * w0 + nd.y * w1 + nd.z * w2 + nd.w * w3;               \
        }                                                                      \
        STORE0; STORE1; STORE2; STORE3;                                        \
    }
#define STAGE_W(Wg)                                                            \
    _Pragma("unroll")                                                          \
    for (int c = 0; c < 8; ++c)                                                \
        *(float4*)&w_s2[t * 4 + c * 1024] =                                    \
            *(const float4*)&(Wg)[(size_t)h * (DM * QK) + t * 4 + c * 1024];

    // query (scaled, log2-domain) -> qtmp_s (f32) + qbf (bf16)
    PROJ_LOOP(
        { float v = a0 * scale; qtmp_s[nb][q] = v;      qbf[((size_t)h * NN + n0 + nb) * 32 + q] = f2bf(v); },
        { float v = a1 * scale; qtmp_s[nb + 8][q] = v;  qbf[((size_t)h * NN + n0 + nb + 8) * 32 + q] = f2bf(v); },
        { float v = a2 * scale; qtmp_s[nb + 16][q] = v; qbf[((size_t)h * NN + n0 + nb + 16) * 32 + q] = f2bf(v); },
        { float v = a3 * scale; qtmp_s[nb + 24][q] = v; qbf[((size_t)h * NN + n0 + nb + 24) * 32 + q] = f2bf(v); })
    __syncthreads();
    STAGE_W(nkt_g)
    __syncthreads();
    // node_key -> bf16 [h][m][q]
    PROJ_LOOP(
        { nk_ws[((size_t)h * NN + n0 + nb) * 32 + q] = f2bf(a0); },
        { nk_ws[((size_t)h * NN + n0 + nb + 8) * 32 + q] = f2bf(a1); },
        { nk_ws[((size_t)h * NN + n0 + nb + 16) * 32 + q] = f2bf(a2); },
        { nk_ws[((size_t)h * NN + n0 + nb + 24) * 32 + q] = f2bf(a3); })
    __syncthreads();
    STAGE_W(nvt_g)
    __syncthreads();
    // node_value -> bf16 transposed [h][v][n]
    PROJ_LOOP(
        { nvT_ws[((size_t)h * 32 + q) * NN + n0 + nb] = f2bf(a0); },
        { nvT_ws[((size_t)h * 32 + q) * NN + n0 + nb + 8] = f2bf(a1); },
        { nvT_ws[((size_t)h * 32 + q) * NN + n0 + nb + 16] = f2bf(a2); },
        { nvT_ws[((size_t)h * 32 + q) * NN + n0 + nb + 24] = f2bf(a3); })
#undef PROJ_LOOP
#undef STAGE_W
    __syncthreads();
    // qe[h,n,e] = sum_q qtmp[n][q] * ek[e][q]   (scaled) -> bf16
#pragma unroll
    for (int c = 0; c < 2; ++c) {
        const int idx = t + c * 256;
        const int nl = idx >> 4, e = idx & 15;
        float s = 0.f;
#pragma unroll
        for (int qq = 0; qq < 32; ++qq) s = fmaf(qtmp_s[nl][qq], ek_g[e * 32 + qq], s);
        qebf[((size_t)h * NN + n0 + nl) * 16 + e] = f2bf(s);
    }
}

// ---------- K2: fused MFMA attention, 2-barrier schedule (round-9 measured best) ----------
// grid 512 = 128 n-tiles(16 rows) * 4 m-chunks(512 m each), 512 thr = 8 waves = 8 heads
__global__ __launch_bounds__(512, 4) void k2_attn(
    const float* __restrict__ ee_g, const u16* __restrict__ qbf,
    const u16* __restrict__ qebf, const u16* __restrict__ nk_g,
    const u16* __restrict__ nvT_g, float* __restrict__ accv_ws,
    float* __restrict__ acce_ws, float* __restrict__ ml_ws) {
    // natural ee [16n][32m][16e], SINGLE buffer (written P2(it) for it+1, read P1(it+1))
    __shared__ __align__(16) u16 ee_s[16 * 520];
    // transposed ee [16n][16e][36m], DOUBLE buffer (written P1(it), read P3(it))
    __shared__ __align__(16) u16 eeT_s[2][16 * 576];
    // edge logits f32 [16n][32m][8h] (m-stride 8, n-stride 260)
    __shared__ __align__(16) float el_s[16 * 260];
    // P bf16 [16n][8h][32m] (n-stride 264)
    __shared__ __align__(16) u16 p_s[16 * 264];
    // rescale factors f32 [16n][8h]
    __shared__ float a_s[16 * 8];

    const int t = threadIdx.x;
    const int w = t >> 6;          // wave = head
    const int l = t & 63;
    const int col = l & 15;
    const int g = l >> 4;          // 0..3
    const int h = w;
    const int nt = blockIdx.x >> 2;
    const int ck = blockIdx.x & 3;
    const int n0 = nt * 16;
    const int mbase = ck * 512;
    // staging role: n-row sn, m-pair sj (m=2sj,2sj+1), e-half seh (e=8seh..)
    const int sn = t >> 5, sj = (t >> 1) & 15, seh = t & 1;

    // persistent fragments
    const bf16x8 Qfrag = *(const bf16x8*)&qbf[((size_t)h * NN + n0 + col) * 32 + 8 * g];
    bf16x8 qeA[2];
#pragma unroll
    for (int s2 = 0; s2 < 2; ++s2) {
        bf16x8 z = {0, 0, 0, 0, 0, 0, 0, 0};
        if (col < 8 && g < 2)
            z = *(const bf16x8*)&qebf[((size_t)col * NN + n0 + 2 * w + s2) * 16 + 8 * g];
        qeA[s2] = z;
    }

    f32x4 accpv0 = {0.f, 0.f, 0.f, 0.f}, accpv1 = {0.f, 0.f, 0.f, 0.f};
    f32x4 acce0 = {0.f, 0.f, 0.f, 0.f}, acce1 = {0.f, 0.f, 0.f, 0.f};
    float M = -INFINITY, Ls = 0.f;

    // chunk regs + K/V prefetch regs
    float4 r0, r1, r2, r3;
    bf16x8 Kf0, Kf1, Vf0, Vf1;
    {
        const float* src = ee_g + ((size_t)(n0 + sn) * NN + mbase + 2 * sj) * 16 + seh * 8;
        r0 = *(const float4*)(src);
        r1 = *(const float4*)(src + 4);
        r2 = *(const float4*)(src + 16);
        r3 = *(const float4*)(src + 20);
        Kf0 = *(const bf16x8*)&nk_g[((size_t)h * NN + mbase + col) * 32 + 8 * g];
        Kf1 = *(const bf16x8*)&nk_g[((size_t)h * NN + mbase + 16 + col) * 32 + 8 * g];
        Vf0 = *(const bf16x8*)&nvT_g[((size_t)h * 32 + col) * NN + mbase + 8 * g];
        Vf1 = *(const bf16x8*)&nvT_g[((size_t)h * 32 + 16 + col) * NN + mbase + 8 * g];
        // stage chunk 0 natural
        *(uint4*)&ee_s[sn * 520 + (2 * sj) * 16 + seh * 8] =
            make_uint4(cvt2(r0.x, r0.y), cvt2(r0.z, r0.w), cvt2(r1.x, r1.y), cvt2(r1.z, r1.w));
        *(uint4*)&ee_s[sn * 520 + (2 * sj + 1) * 16 + seh * 8] =
            make_uint4(cvt2(r2.x, r2.y), cvt2(r2.z, r2.w), cvt2(r3.x, r3.y), cvt2(r3.z, r3.w));
    }
    LBAR();

    const f32x4 zf = {0.f, 0.f, 0.f, 0.f};

#pragma unroll 1
    for (int it = 0; it < 16; ++it) {
        const int m0 = mbase + it * 32;

        // ================= P1 =================
        // eeT write for chunk it from regs (m-pairs packed)
        {
            u32* dstT = (u32*)&eeT_s[it & 1][0] + sn * 288 + seh * 144 + sj;
            dstT[0 * 18] = cvt2(r0.x, r2.x);
            dstT[1 * 18] = cvt2(r0.y, r2.y);
            dstT[2 * 18] = cvt2(r0.z, r2.z);
            dstT[3 * 18] = cvt2(r0.w, r2.w);
            dstT[4 * 18] = cvt2(r1.x, r3.x);
            dstT[5 * 18] = cvt2(r1.y, r3.y);
            dstT[6 * 18] = cvt2(r1.z, r3.z);
            dstT[7 * 18] = cvt2(r1.w, r3.w);
        }
        // prefetch chunk it+1 (reg-destined; rides across both barriers)
        if (it < 15) {
            const float* src = ee_g + ((size_t)(n0 + sn) * NN + m0 + 32 + 2 * sj) * 16 + seh * 8;
            r0 = *(const float4*)(src);
            r1 = *(const float4*)(src + 4);
            r2 = *(const float4*)(src + 16);
            r3 = *(const float4*)(src + 20);
        }
        // step A: node logits S^T = K·Q^T (K prefetched previous P3)
        f32x4 sn0 = __builtin_amdgcn_mfma_f32_16x16x32_bf16(Kf0, Qfrag, zf, 0, 0, 0);
        f32x4 sn1 = __builtin_amdgcn_mfma_f32_16x16x32_bf16(Kf1, Qfrag, zf, 0, 0, 0);
        // step B: edge logits per n-slot: D[h][m] = qe_n · ee_n^T
#pragma unroll
        for (int s2 = 0; s2 < 2; ++s2) {
            const int nsl = 2 * w + s2;
#pragma unroll
            for (int s = 0; s < 2; ++s) {
                bf16x8 Bf = {0, 0, 0, 0, 0, 0, 0, 0};
                if (g < 2)
                    Bf = *(const bf16x8*)&ee_s[nsl * 520 + (s * 16 + col) * 16 + 8 * g];
                f32x4 d = __builtin_amdgcn_mfma_f32_16x16x32_bf16(qeA[s2], Bf, zf, 0, 0, 0);
                if (l < 32)   // rows h = 4g+reg < 8
                    *(float4*)&el_s[nsl * 260 + (s * 16 + col) * 8 + 4 * g] =
                        make_float4(d[0], d[1], d[2], d[3]);
            }
        }
        LBAR();  // BAR1: edge-logit exchange

        // ================= P2 =================
        {
            const float* elp = &el_s[col * 260 + h];
            float lv[8];
#pragma unroll
            for (int r = 0; r < 4; ++r) {
                lv[r]     = sn0[r] + elp[(4 * g + r) * 8];
                lv[4 + r] = sn1[r] + elp[(16 + 4 * g + r) * 8];
            }
            float tm = fmaxf(fmaxf(fmaxf(lv[0], lv[1]), fmaxf(lv[2], lv[3])),
                             fmaxf(fmaxf(lv[4], lv[5]), fmaxf(lv[6], lv[7])));
            tm = fmaxf(tm, __shfl_xor(tm, 16));
            tm = fmaxf(tm, __shfl_xor(tm, 32));
            const float nM = fmaxf(M, tm);
            const float a = fexp2(M - nM);   // log2-domain
            M = nM;
            Ls *= a;
#pragma unroll
            for (int r = 0; r < 4; ++r) { accpv0[r] *= a; accpv1[r] *= a; }
            float p[8];
#pragma unroll
            for (int i = 0; i < 8; ++i) { p[i] = fexp2(lv[i] - nM); Ls += p[i]; }
            uint2 pk0, pk1;
            pk0.x = cvt2(p[0], p[1]); pk0.y = cvt2(p[2], p[3]);
            pk1.x = cvt2(p[4], p[5]); pk1.y = cvt2(p[6], p[7]);
            *(uint2*)&p_s[col * 264 + h * 32 + 4 * g] = pk0;
            *(uint2*)&p_s[col * 264 + h * 32 + 16 + 4 * g] = pk1;
            if (l < 16) a_s[col * 8 + h] = a;
        }
        // PV: own-wave P (per-wave LDS ops are in-order; no barrier needed)
        {
            const bf16x8 Pf = *(const bf16x8*)&p_s[col * 264 + h * 32 + 8 * g];
            accpv0 = __builtin_amdgcn_mfma_f32_16x16x32_bf16(Vf0, Pf, accpv0, 0, 0, 0);
            accpv1 = __builtin_amdgcn_mfma_f32_16x16x32_bf16(Vf1, Pf, accpv1, 0, 0, 0);
        }
        // staging: write chunk it+1 natural (vmcnt wait auto-inserted here)
        if (it < 15) {
            *(uint4*)&ee_s[sn * 520 + (2 * sj) * 16 + seh * 8] =
                make_uint4(cvt2(r0.x, r0.y), cvt2(r0.z, r0.w), cvt2(r1.x, r1.y), cvt2(r1.z, r1.w));
            *(uint4*)&ee_s[sn * 520 + (2 * sj + 1) * 16 + seh * 8] =
                make_uint4(cvt2(r2.x, r2.y), cvt2(r2.z, r2.w), cvt2(r3.x, r3.y), cvt2(r3.z, r3.w));
        }
        LBAR();  // BAR2: P/a exchange + ee_s handoff

        // ================= P3 ================= (no trailing barrier)
        {
            const bf16x8 Pn0 = *(const bf16x8*)&p_s[(2 * w + 0) * 264 + (col & 7) * 32 + 8 * g];
            const bf16x8 Pn1 = *(const bf16x8*)&p_s[(2 * w + 1) * 264 + (col & 7) * 32 + 8 * g];
            const bf16x8 B0 = *(const bf16x8*)&eeT_s[it & 1][(2 * w + 0) * 576 + col * 36 + 8 * g];
            const bf16x8 B1 = *(const bf16x8*)&eeT_s[it & 1][(2 * w + 1) * 576 + col * 36 + 8 * g];
            const float4 av0 = *(const float4*)&a_s[(2 * w + 0) * 8 + ((4 * g) & 7)];
            const float4 av1 = *(const float4*)&a_s[(2 * w + 1) * 8 + ((4 * g) & 7)];
            acce0[0] *= av0.x; acce0[1] *= av0.y; acce0[2] *= av0.z; acce0[3] *= av0.w;
            acce1[0] *= av1.x; acce1[1] *= av1.y; acce1[2] *= av1.z; acce1[3] *= av1.w;
            acce0 = __builtin_amdgcn_mfma_f32_16x16x32_bf16(Pn0, B0, acce0, 0, 0, 0);
            acce1 = __builtin_amdgcn_mfma_f32_16x16x32_bf16(Pn1, B1, acce1, 0, 0, 0);
        }
        // K/V prefetch for it+1 (L2-resident; consumed next P1/P2)
        if (it < 15) {
            Kf0 = *(const bf16x8*)&nk_g[((size_t)h * NN + m0 + 32 + col) * 32 + 8 * g];
            Kf1 = *(const bf16x8*)&nk_g[((size_t)h * NN + m0 + 48 + col) * 32 + 8 * g];
            Vf0 = *(const bf16x8*)&nvT_g[((size_t)h * 32 + col) * NN + m0 + 32 + 8 * g];
            Vf1 = *(const bf16x8*)&nvT_g[((size_t)h * 32 + 16 + col) * NN + m0 + 32 + 8 * g];
        }
    }

    // epilogue
    Ls += __shfl_xor(Ls, 16);
    Ls += __shfl_xor(Ls, 32);

    {
        float* avp = accv_ws + (((size_t)ck * 8 + h) * NN + n0 + col) * 32;
#pragma unroll
        for (int reg = 0; reg < 4; ++reg) {
            avp[4 * g + reg] = accpv0[reg];
            avp[16 + 4 * g + reg] = accpv1[reg];
        }
    }
    if (l < 32) {
#pragma unroll
        for (int s2 = 0; s2 < 2; ++s2) {
            const f32x4 acc = (s2 == 0) ? acce0 : acce1;
#pragma unroll
            for (int reg = 0; reg < 4; ++reg) {
                const int hr = 4 * g + reg;
                acce_ws[(((size_t)ck * 8 + hr) * NN + n0 + 2 * w + s2) * 16 + col] = acc[reg];
            }
        }
    }
    if (l < 16) {
        float* mlp = ml_ws + (((size_t)ck * 8 + h) * NN + n0 + col) * 2;
        mlp[0] = M;   // log2-domain
        mlp[1] = Ls;
    }
}

// ---------- K3: combine 4 m-chunks + edge-value projection + output GEMM ----------
// grid 1024 (2 n-rows each), ~3 KB LDS -> 4 blocks/CU for latency hiding on the ot_g loop
__global__ __launch_bounds__(256) void k3_combine(
    const float* __restrict__ accv_ws, const float* __restrict__ acce_ws,
    const float* __restrict__ ml_ws, const float* __restrict__ ev_g,
    const float* __restrict__ ot_g, float* __restrict__ out_g) {
    __shared__ float w_s[16][4];
    __shared__ float ae_s[2 * 8 * 16];
    __shared__ __align__(16) float av_s[256 * 2];  // [k=h*32+v][n_l]
    const int t = threadIdx.x;
    const int n0 = blockIdx.x * 2;
    if (t < 16) {
        const int h = t >> 1, nl = t & 1, gn = n0 + nl;
        float Mc[4], Lc[4];
#pragma unroll
        for (int c = 0; c < 4; ++c) {
            Mc[c] = ml_ws[(((size_t)c * 8 + h) * NN + gn) * 2 + 0];
            Lc[c] = ml_ws[(((size_t)c * 8 + h) * NN + gn) * 2 + 1];
        }
        float Mx = fmaxf(fmaxf(Mc[0], Mc[1]), fmaxf(Mc[2], Mc[3]));
        float ex[4], den = 0.f;
#pragma unroll
        for (int c = 0; c < 4; ++c) { ex[c] = __builtin_amdgcn_exp2f(Mc[c] - Mx); den += ex[c] * Lc[c]; }
        const float inv = 1.0f / den;
#pragma unroll
        for (int c = 0; c < 4; ++c) w_s[t][c] = ex[c] * inv;
    }
    __syncthreads();
    {
        const int idx = t;             // 256 = 2n*8h*16e
        const int nl = idx >> 7, h = (idx >> 4) & 7, e = idx & 15;
        const int gn = n0 + nl;
        float s = 0.f;
#pragma unroll
        for (int c = 0; c < 4; ++c)
            s += w_s[h * 2 + nl][c] * acce_ws[(((size_t)c * 8 + h) * NN + gn) * 16 + e];
        ae_s[(nl * 8 + h) * 16 + e] = s;
    }
    __syncthreads();
#pragma unroll
    for (int c2 = 0; c2 < 2; ++c2) {
        const int idx = t + c2 * 256;  // 512 = 2n*8h*32v
        const int nl = idx >> 8, h = (idx >> 5) & 7, v = idx & 31;
        const int gn = n0 + nl;
        float x = 0.f;
#pragma unroll
        for (int c = 0; c < 4; ++c)
            x += w_s[h * 2 + nl][c] * accv_ws[(((size_t)c * 8 + h) * NN + gn) * 32 + v];
        const float* aep = &ae_s[(nl * 8 + h) * 16];
#pragma unroll
        for (int e = 0; e < 16; ++e) x = fmaf(aep[e], ev_g[e * 32 + v], x);
        av_s[(h * 32 + v) * 2 + nl] = x;
    }
    __syncthreads();
    {
        const int o = t;
        float r0 = 0, r1 = 0;
#pragma unroll 8
        for (int k = 0; k < 256; ++k) {
            const float w = ot_g[k * 256 + o];
            const float* av = &av_s[k * 2];
            r0 = fmaf(av[0], w, r0);
            r1 = fmaf(av[1], w, r1);
        }
        out_g[(size_t)(n0 + 0) * 256 + o] = r0;
        out_g[(size_t)(n0 + 1) * 256 + o] = r1;
    }
}

extern "C" void kernel_launch(void* const* d_in, const int* in_sizes, int n_in,
                              void* d_out, int out_size, void* d_ws, size_t ws_size,
                              hipStream_t stream) {
    (void)in_sizes; (void)n_in; (void)out_size; (void)ws_size;
    const float* ee = (const float*)d_in[0];
    const float* node = (const float*)d_in[1];
    const float* qt = (const float*)d_in[2];
    const float* nkt = (const float*)d_in[3];
    const float* ek = (const float*)d_in[4];
    const float* nvt = (const float*)d_in[5];
    const float* ev = (const float*)d_in[6];
    const float* ot = (const float*)d_in[7];
    float* out = (float*)d_out;

    char* ws = (char*)d_ws;
    u16* qbf = (u16*)(ws);                             // 1 MB  [8][2048][32] bf16
    u16* qebf = (u16*)(ws + (1u << 20));               // 0.5 MB [8][2048][16] bf16
    u16* nk_ws = (u16*)(ws + (1u << 20) + (1u << 19)); // 1 MB  [8][2048][32] bf16
    u16* nvT_ws = (u16*)(ws + (2u << 20) + (1u << 19));// 1 MB [8][32][2048] bf16
    float* accv_ws = (float*)(ws + (3u << 20) + (1u << 19)); // 8 MB [4][8][2048][32]
    float* acce_ws = (float*)(ws + (11u << 20) + (1u << 19));// 4 MB [4][8][2048][16]
    float* ml_ws = (float*)(ws + (15u << 20) + (1u << 19));  // 0.5 MB [4][8][2048][2]

    hipLaunchKernelGGL(k1_precompute, dim3(512), dim3(256), 0, stream,
                       node, qt, nkt, nvt, ek, qbf, qebf, nk_ws, nvT_ws);
    hipLaunchKernelGGL(k2_attn, dim3(512), dim3(512), 0, stream,
                       ee, qbf, qebf, nk_ws, nvT_ws, accv_ws, acce_ws, ml_ws);
    hipLaunchKernelGGL(k3_combine, dim3(1024), dim3(256), 0, stream,
                       accv_ws, acce_ws, ml_ws, ev, ot, out);
}

// Round 16
// 125.236 us; speedup vs baseline: 1.0074x; 1.0074x over previous
//
#include <hip/hip_runtime.h>
#include <hip/hip_bf16.h>

typedef unsigned short u16;
typedef unsigned int u32;
typedef __attribute__((ext_vector_type(8))) short bf16x8;
typedef __attribute__((ext_vector_type(4))) float f32x4;

#define NN 2048
#define DM 256
#define ED 16
#define HH 8
#define QK 32
#define VV 32
#define OUTD 256

// LDS-only barrier: drain LDS ops, then barrier, WITHOUT draining vmcnt.
#define LBAR() asm volatile("s_waitcnt lgkmcnt(0)\n\ts_barrier" ::: "memory")

// ---------- helpers ----------
__device__ __forceinline__ float fexp2(float x) { return __builtin_amdgcn_exp2f(x); }
__device__ __forceinline__ u16 f2bf(float f) {
    __hip_bfloat16 h = __float2bfloat16(f);
    return *reinterpret_cast<u16*>(&h);
}
__device__ __forceinline__ u32 cvt2(float a, float b) {
    __hip_bfloat162 h = __float22bfloat162_rn(make_float2(a, b));
    return *reinterpret_cast<u32*>(&h);
}

// ---------- K1: projections (weights staged through LDS) ----------
// grid 512 = 8 h * 64 n-tiles(32 rows), 256 thr
// Scale includes log2(e): logits come out in log2 domain (k2/k3 use exp2).
__global__ __launch_bounds__(256) void k1_precompute(
    const float* __restrict__ node_g, const float* __restrict__ qt_g,
    const float* __restrict__ nkt_g, const float* __restrict__ nvt_g,
    const float* __restrict__ ek_g,
    u16* __restrict__ qbf, u16* __restrict__ qebf,
    u16* __restrict__ nk_ws, u16* __restrict__ nvT_ws) {
    __shared__ __align__(16) float node_s[32][256];   // 32 KB
    __shared__ __align__(16) float qtmp_s[32][32];    // 4 KB
    __shared__ __align__(16) float w_s2[256 * 32];    // 32 KB (one weight matrix)
    const int t = threadIdx.x;
    const int h = blockIdx.x >> 6;
    const int n0 = (blockIdx.x & 63) * 32;
    // stage node rows (32 x 256 f32) + first weight (qt)
#pragma unroll
    for (int c = 0; c < 8; ++c) {
        const int ci = t + c * 256;
        const int nl = ci >> 6, d4 = ci & 63;
        *(float4*)&node_s[nl][d4 * 4] =
            *(const float4*)&node_g[(size_t)(n0 + nl) * 256 + d4 * 4];
    }
#pragma unroll
    for (int c = 0; c < 8; ++c)
        *(float4*)&w_s2[t * 4 + c * 1024] =
            *(const float4*)&qt_g[(size_t)h * (DM * QK) + t * 4 + c * 1024];
    __syncthreads();
    const int q = t & 31, nb = t >> 5;
    const float scale = 0.17677669529663689f * 1.4426950408889634f; // (1/sqrt32)*log2e

// PROJ reads the staged weight from LDS: thread q reads column q (bank q, broadcast across nb)
#define PROJ_LOOP(STORE0, STORE1, STORE2, STORE3)                              \
    {                                                                          \
        float a0 = 0.f, a1 = 0.f, a2 = 0.f, a3 = 0.f;                          \
        for (int d4 = 0; d4 < 64; ++d4) {                                      \
            const float w0 = w_s2[(d4 * 4 + 0) * 32 + q];                      \
            const float w1 = w_s2[(d4 * 4 + 1) * 32 + q];                      \
            const float w2 = w_s2[(d4 * 4 + 2) * 32 + q];                      \
            const float w3 = w_s2[(d4 * 4 + 3) * 32 + q];                      \
            float4 nd;                                                         \
            nd = *(const float4*)&node_s[nb][d4 * 4];                          \
            a0 += nd.x * w0 + nd.y * w1 + nd.z * w2 + nd.w * w3;               \
            nd = *(const float4*)&node_s[nb + 8][d4 * 4];                      \
            a1 += nd.x * w0 + nd.y * w1 + nd.z * w2 + nd.w * w3;               \
            nd = *(const float4*)&node_s[nb + 16][d4 * 4];                     \
            a2 += nd.x * w0 + nd.y * w1 + nd.z * w2 + nd.w * w3;               \
            nd = *(const float4*)&node_s[nb + 24][d4 * 4];                     \
            a3 += nd.x * w0 + nd.y * w1 + nd.z * w2 + nd.w * w3;               \
        }                                                                      \
        STORE0; STORE1; STORE2; STORE3;                                        \
    }
#define STAGE_W(Wg)                                                            \
    _Pragma("unroll")                                                          \
    for (int c = 0; c < 8; ++c)                                                \
        *(float4*)&w_s2[t * 4 + c * 1024] =                                    \
            *(const float4*)&(Wg)[(size_t)h * (DM * QK) + t * 4 + c * 1024];

    // query (scaled, log2-domain) -> qtmp_s (f32) + qbf (bf16)
    PROJ_LOOP(
        { float v = a0 * scale; qtmp_s[nb][q] = v;      qbf[((size_t)h * NN + n0 + nb) * 32 + q] = f2bf(v); },
        { float v = a1 * scale; qtmp_s[nb + 8][q] = v;  qbf[((size_t)h * NN + n0 + nb + 8) * 32 + q] = f2bf(v); },
        { float v = a2 * scale; qtmp_s[nb + 16][q] = v; qbf[((size_t)h * NN + n0 + nb + 16) * 32 + q] = f2bf(v); },
        { float v = a3 * scale; qtmp_s[nb + 24][q] = v; qbf[((size_t)h * NN + n0 + nb + 24) * 32 + q] = f2bf(v); })
    __syncthreads();
    STAGE_W(nkt_g)
    __syncthreads();
    // node_key -> bf16 [h][m][q]
    PROJ_LOOP(
        { nk_ws[((size_t)h * NN + n0 + nb) * 32 + q] = f2bf(a0); },
        { nk_ws[((size_t)h * NN + n0 + nb + 8) * 32 + q] = f2bf(a1); },
        { nk_ws[((size_t)h * NN + n0 + nb + 16) * 32 + q] = f2bf(a2); },
        { nk_ws[((size_t)h * NN + n0 + nb + 24) * 32 + q] = f2bf(a3); })
    __syncthreads();
    STAGE_W(nvt_g)
    __syncthreads();
    // node_value -> bf16 transposed [h][v][n]
    PROJ_LOOP(
        { nvT_ws[((size_t)h * 32 + q) * NN + n0 + nb] = f2bf(a0); },
        { nvT_ws[((size_t)h * 32 + q) * NN + n0 + nb + 8] = f2bf(a1); },
        { nvT_ws[((size_t)h * 32 + q) * NN + n0 + nb + 16] = f2bf(a2); },
        { nvT_ws[((size_t)h * 32 + q) * NN + n0 + nb + 24] = f2bf(a3); })
#undef PROJ_LOOP
#undef STAGE_W
    __syncthreads();
    // qe[h,n,e] = sum_q qtmp[n][q] * ek[e][q]   (scaled) -> bf16
#pragma unroll
    for (int c = 0; c < 2; ++c) {
        const int idx = t + c * 256;
        const int nl = idx >> 4, e = idx & 15;
        float s = 0.f;
#pragma unroll
        for (int qq = 0; qq < 32; ++qq) s = fmaf(qtmp_s[nl][qq], ek_g[e * 32 + qq], s);
        qebf[((size_t)h * NN + n0 + nl) * 16 + e] = f2bf(s);
    }
}

// ---------- K2: fused MFMA attention, 2-barrier schedule (round-9 measured best) ----------
// grid 512 = 128 n-tiles(16 rows) * 4 m-chunks(512 m each), 512 thr = 8 waves = 8 heads
__global__ __launch_bounds__(512, 4) void k2_attn(
    const float* __restrict__ ee_g, const u16* __restrict__ qbf,
    const u16* __restrict__ qebf, const u16* __restrict__ nk_g,
    const u16* __restrict__ nvT_g, float* __restrict__ accv_ws,
    float* __restrict__ acce_ws, float* __restrict__ ml_ws) {
    // natural ee [16n][32m][16e], SINGLE buffer (written P2(it) for it+1, read P1(it+1))
    __shared__ __align__(16) u16 ee_s[16 * 520];
    // transposed ee [16n][16e][36m], DOUBLE buffer (written P1(it), read P3(it))
    __shared__ __align__(16) u16 eeT_s[2][16 * 576];
    // edge logits f32 [16n][32m][8h] (m-stride 8, n-stride 260)
    __shared__ __align__(16) float el_s[16 * 260];
    // P bf16 [16n][8h][32m] (n-stride 264)
    __shared__ __align__(16) u16 p_s[16 * 264];
    // rescale factors f32 [16n][8h]
    __shared__ float a_s[16 * 8];

    const int t = threadIdx.x;
    const int w = t >> 6;          // wave = head
    const int l = t & 63;
    const int col = l & 15;
    const int g = l >> 4;          // 0..3
    const int h = w;
    const int nt = blockIdx.x >> 2;
    const int ck = blockIdx.x & 3;
    const int n0 = nt * 16;
    const int mbase = ck * 512;
    // staging role: n-row sn, m-pair sj (m=2sj,2sj+1), e-half seh (e=8seh..)
    const int sn = t >> 5, sj = (t >> 1) & 15, seh = t & 1;

    // persistent fragments
    const bf16x8 Qfrag = *(const bf16x8*)&qbf[((size_t)h * NN + n0 + col) * 32 + 8 * g];
    bf16x8 qeA[2];
#pragma unroll
    for (int s2 = 0; s2 < 2; ++s2) {
        bf16x8 z = {0, 0, 0, 0, 0, 0, 0, 0};
        if (col < 8 && g < 2)
            z = *(const bf16x8*)&qebf[((size_t)col * NN + n0 + 2 * w + s2) * 16 + 8 * g];
        qeA[s2] = z;
    }

    f32x4 accpv0 = {0.f, 0.f, 0.f, 0.f}, accpv1 = {0.f, 0.f, 0.f, 0.f};
    f32x4 acce0 = {0.f, 0.f, 0.f, 0.f}, acce1 = {0.f, 0.f, 0.f, 0.f};
    float M = -INFINITY, Ls = 0.f;

    // chunk regs + K/V prefetch regs
    float4 r0, r1, r2, r3;
    bf16x8 Kf0, Kf1, Vf0, Vf1;
    {
        const float* src = ee_g + ((size_t)(n0 + sn) * NN + mbase + 2 * sj) * 16 + seh * 8;
        r0 = *(const float4*)(src);
        r1 = *(const float4*)(src + 4);
        r2 = *(const float4*)(src + 16);
        r3 = *(const float4*)(src + 20);
        Kf0 = *(const bf16x8*)&nk_g[((size_t)h * NN + mbase + col) * 32 + 8 * g];
        Kf1 = *(const bf16x8*)&nk_g[((size_t)h * NN + mbase + 16 + col) * 32 + 8 * g];
        Vf0 = *(const bf16x8*)&nvT_g[((size_t)h * 32 + col) * NN + mbase + 8 * g];
        Vf1 = *(const bf16x8*)&nvT_g[((size_t)h * 32 + 16 + col) * NN + mbase + 8 * g];
        // stage chunk 0 natural
        *(uint4*)&ee_s[sn * 520 + (2 * sj) * 16 + seh * 8] =
            make_uint4(cvt2(r0.x, r0.y), cvt2(r0.z, r0.w), cvt2(r1.x, r1.y), cvt2(r1.z, r1.w));
        *(uint4*)&ee_s[sn * 520 + (2 * sj + 1) * 16 + seh * 8] =
            make_uint4(cvt2(r2.x, r2.y), cvt2(r2.z, r2.w), cvt2(r3.x, r3.y), cvt2(r3.z, r3.w));
    }
    LBAR();

    const f32x4 zf = {0.f, 0.f, 0.f, 0.f};

#pragma unroll 1
    for (int it = 0; it < 16; ++it) {
        const int m0 = mbase + it * 32;

        // ================= P1 =================
        // eeT write for chunk it from regs (m-pairs packed)
        {
            u32* dstT = (u32*)&eeT_s[it & 1][0] + sn * 288 + seh * 144 + sj;
            dstT[0 * 18] = cvt2(r0.x, r2.x);
            dstT[1 * 18] = cvt2(r0.y, r2.y);
            dstT[2 * 18] = cvt2(r0.z, r2.z);
            dstT[3 * 18] = cvt2(r0.w, r2.w);
            dstT[4 * 18] = cvt2(r1.x, r3.x);
            dstT[5 * 18] = cvt2(r1.y, r3.y);
            dstT[6 * 18] = cvt2(r1.z, r3.z);
            dstT[7 * 18] = cvt2(r1.w, r3.w);
        }
        // prefetch chunk it+1 (reg-destined; rides across both barriers)
        if (it < 15) {
            const float* src = ee_g + ((size_t)(n0 + sn) * NN + m0 + 32 + 2 * sj) * 16 + seh * 8;
            r0 = *(const float4*)(src);
            r1 = *(const float4*)(src + 4);
            r2 = *(const float4*)(src + 16);
            r3 = *(const float4*)(src + 20);
        }
        // step A: node logits S^T = K·Q^T (K prefetched previous P3)
        f32x4 sn0 = __builtin_amdgcn_mfma_f32_16x16x32_bf16(Kf0, Qfrag, zf, 0, 0, 0);
        f32x4 sn1 = __builtin_amdgcn_mfma_f32_16x16x32_bf16(Kf1, Qfrag, zf, 0, 0, 0);
        // step B: edge logits per n-slot: D[h][m] = qe_n · ee_n^T
#pragma unroll
        for (int s2 = 0; s2 < 2; ++s2) {
            const int nsl = 2 * w + s2;
#pragma unroll
            for (int s = 0; s < 2; ++s) {
                bf16x8 Bf = {0, 0, 0, 0, 0, 0, 0, 0};
                if (g < 2)
                    Bf = *(const bf16x8*)&ee_s[nsl * 520 + (s * 16 + col) * 16 + 8 * g];
                f32x4 d = __builtin_amdgcn_mfma_f32_16x16x32_bf16(qeA[s2], Bf, zf, 0, 0, 0);
                if (l < 32)   // rows h = 4g+reg < 8
                    *(float4*)&el_s[nsl * 260 + (s * 16 + col) * 8 + 4 * g] =
                        make_float4(d[0], d[1], d[2], d[3]);
            }
        }
        LBAR();  // BAR1: edge-logit exchange

        // ================= P2 =================
        {
            const float* elp = &el_s[col * 260 + h];
            float lv[8];
#pragma unroll
            for (int r = 0; r < 4; ++r) {
                lv[r]     = sn0[r] + elp[(4 * g + r) * 8];
                lv[4 + r] = sn1[r] + elp[(16 + 4 * g + r) * 8];
            }
            float tm = fmaxf(fmaxf(fmaxf(lv[0], lv[1]), fmaxf(lv[2], lv[3])),
                             fmaxf(fmaxf(lv[4], lv[5]), fmaxf(lv[6], lv[7])));
            tm = fmaxf(tm, __shfl_xor(tm, 16));
            tm = fmaxf(tm, __shfl_xor(tm, 32));
            const float nM = fmaxf(M, tm);
            const float a = fexp2(M - nM);   // log2-domain
            M = nM;
            Ls *= a;
#pragma unroll
            for (int r = 0; r < 4; ++r) { accpv0[r] *= a; accpv1[r] *= a; }
            float p[8];
#pragma unroll
            for (int i = 0; i < 8; ++i) { p[i] = fexp2(lv[i] - nM); Ls += p[i]; }
            uint2 pk0, pk1;
            pk0.x = cvt2(p[0], p[1]); pk0.y = cvt2(p[2], p[3]);
            pk1.x = cvt2(p[4], p[5]); pk1.y = cvt2(p[6], p[7]);
            *(uint2*)&p_s[col * 264 + h * 32 + 4 * g] = pk0;
            *(uint2*)&p_s[col * 264 + h * 32 + 16 + 4 * g] = pk1;
            if (l < 16) a_s[col * 8 + h] = a;
        }
        // PV: own-wave P (per-wave LDS ops are in-order; no barrier needed)
        {
            const bf16x8 Pf = *(const bf16x8*)&p_s[col * 264 + h * 32 + 8 * g];
            accpv0 = __builtin_amdgcn_mfma_f32_16x16x32_bf16(Vf0, Pf, accpv0, 0, 0, 0);
            accpv1 = __builtin_amdgcn_mfma_f32_16x16x32_bf16(Vf1, Pf, accpv1, 0, 0, 0);
        }
        // staging: write chunk it+1 natural (vmcnt wait auto-inserted here)
        if (it < 15) {
            *(uint4*)&ee_s[sn * 520 + (2 * sj) * 16 + seh * 8] =
                make_uint4(cvt2(r0.x, r0.y), cvt2(r0.z, r0.w), cvt2(r1.x, r1.y), cvt2(r1.z, r1.w));
            *(uint4*)&ee_s[sn * 520 + (2 * sj + 1) * 16 + seh * 8] =
                make_uint4(cvt2(r2.x, r2.y), cvt2(r2.z, r2.w), cvt2(r3.x, r3.y), cvt2(r3.z, r3.w));
        }
        LBAR();  // BAR2: P/a exchange + ee_s handoff

        // ================= P3 ================= (no trailing barrier)
        {
            const bf16x8 Pn0 = *(const bf16x8*)&p_s[(2 * w + 0) * 264 + (col & 7) * 32 + 8 * g];
            const bf16x8 Pn1 = *(const bf16x8*)&p_s[(2 * w + 1) * 264 + (col & 7) * 32 + 8 * g];
            const bf16x8 B0 = *(const bf16x8*)&eeT_s[it & 1][(2 * w + 0) * 576 + col * 36 + 8 * g];
            const bf16x8 B1 = *(const bf16x8*)&eeT_s[it & 1][(2 * w + 1) * 576 + col * 36 + 8 * g];
            const float4 av0 = *(const float4*)&a_s[(2 * w + 0) * 8 + ((4 * g) & 7)];
            const float4 av1 = *(const float4*)&a_s[(2 * w + 1) * 8 + ((4 * g) & 7)];
            acce0[0] *= av0.x; acce0[1] *= av0.y; acce0[2] *= av0.z; acce0[3] *= av0.w;
            acce1[0] *= av1.x; acce1[1] *= av1.y; acce1[2] *= av1.z; acce1[3] *= av1.w;
            acce0 = __builtin_amdgcn_mfma_f32_16x16x32_bf16(Pn0, B0, acce0, 0, 0, 0);
            acce1 = __builtin_amdgcn_mfma_f32_16x16x32_bf16(Pn1, B1, acce1, 0, 0, 0);
        }
        // K/V prefetch for it+1 (L2-resident; consumed next P1/P2)
        if (it < 15) {
            Kf0 = *(const bf16x8*)&nk_g[((size_t)h * NN + m0 + 32 + col) * 32 + 8 * g];
            Kf1 = *(const bf16x8*)&nk_g[((size_t)h * NN + m0 + 48 + col) * 32 + 8 * g];
            Vf0 = *(const bf16x8*)&nvT_g[((size_t)h * 32 + col) * NN + m0 + 32 + 8 * g];
            Vf1 = *(const bf16x8*)&nvT_g[((size_t)h * 32 + 16 + col) * NN + m0 + 32 + 8 * g];
        }
    }

    // epilogue
    Ls += __shfl_xor(Ls, 16);
    Ls += __shfl_xor(Ls, 32);

    {
        float* avp = accv_ws + (((size_t)ck * 8 + h) * NN + n0 + col) * 32;
#pragma unroll
        for (int reg = 0; reg < 4; ++reg) {
            avp[4 * g + reg] = accpv0[reg];
            avp[16 + 4 * g + reg] = accpv1[reg];
        }
    }
    if (l < 32) {
#pragma unroll
        for (int s2 = 0; s2 < 2; ++s2) {
            const f32x4 acc = (s2 == 0) ? acce0 : acce1;
#pragma unroll
            for (int reg = 0; reg < 4; ++reg) {
                const int hr = 4 * g + reg;
                acce_ws[(((size_t)ck * 8 + hr) * NN + n0 + 2 * w + s2) * 16 + col] = acc[reg];
            }
        }
    }
    if (l < 16) {
        float* mlp = ml_ws + (((size_t)ck * 8 + h) * NN + n0 + col) * 2;
        mlp[0] = M;   // log2-domain
        mlp[1] = Ls;
    }
}

// ---------- K3: combine 4 m-chunks + edge-value projection + output GEMM ----------
// grid 512 (4 n-rows each) = 2 blocks/CU for latency hiding on the ot_g loop
__global__ __launch_bounds__(256) void k3_combine(
    const float* __restrict__ accv_ws, const float* __restrict__ acce_ws,
    const float* __restrict__ ml_ws, const float* __restrict__ ev_g,
    const float* __restrict__ ot_g, float* __restrict__ out_g) {
    __shared__ float w_s[32][4];
    __shared__ float ae_s[4 * 8 * 16];
    __shared__ __align__(16) float av_s[256 * 4];  // [k=h*32+v][n_l]
    const int t = threadIdx.x;
    const int n0 = blockIdx.x * 4;
    if (t < 32) {
        const int h = t >> 2, nl = t & 3, gn = n0 + nl;
        float Mc[4], Lc[4];
#pragma unroll
        for (int c = 0; c < 4; ++c) {
            Mc[c] = ml_ws[(((size_t)c * 8 + h) * NN + gn) * 2 + 0];
            Lc[c] = ml_ws[(((size_t)c * 8 + h) * NN + gn) * 2 + 1];
        }
        float Mx = fmaxf(fmaxf(Mc[0], Mc[1]), fmaxf(Mc[2], Mc[3]));
        float ex[4], den = 0.f;
#pragma unroll
        for (int c = 0; c < 4; ++c) { ex[c] = __builtin_amdgcn_exp2f(Mc[c] - Mx); den += ex[c] * Lc[c]; }
        const float inv = 1.0f / den;
#pragma unroll
        for (int c = 0; c < 4; ++c) w_s[t][c] = ex[c] * inv;
    }
    __syncthreads();
#pragma unroll
    for (int c2 = 0; c2 < 2; ++c2) {
        const int idx = t + c2 * 256;  // 512 = 4n*8h*16e
        const int nl = idx >> 7, h = (idx >> 4) & 7, e = idx & 15;
        const int gn = n0 + nl;
        float s = 0.f;
#pragma unroll
        for (int c = 0; c < 4; ++c)
            s += w_s[h * 4 + nl][c] * acce_ws[(((size_t)c * 8 + h) * NN + gn) * 16 + e];
        ae_s[(nl * 8 + h) * 16 + e] = s;
    }
    __syncthreads();
#pragma unroll
    for (int c2 = 0; c2 < 4; ++c2) {
        const int idx = t + c2 * 256;  // 1024 = 4n*8h*32v
        const int nl = idx >> 8, h = (idx >> 5) & 7, v = idx & 31;
        const int gn = n0 + nl;
        float x = 0.f;
#pragma unroll
        for (int c = 0; c < 4; ++c)
            x += w_s[h * 4 + nl][c] * accv_ws[(((size_t)c * 8 + h) * NN + gn) * 32 + v];
        const float* aep = &ae_s[(nl * 8 + h) * 16];
#pragma unroll
        for (int e = 0; e < 16; ++e) x = fmaf(aep[e], ev_g[e * 32 + v], x);
        av_s[(h * 32 + v) * 4 + nl] = x;
    }
    __syncthreads();
    {
        const int o = t;
        float r0 = 0, r1 = 0, r2 = 0, r3 = 0;
#pragma unroll 8
        for (int k = 0; k < 256; ++k) {
            const float w = ot_g[k * 256 + o];
            const float* av = &av_s[k * 4];
            r0 = fmaf(av[0], w, r0); r1 = fmaf(av[1], w, r1);
            r2 = fmaf(av[2], w, r2); r3 = fmaf(av[3], w, r3);
        }
        out_g[(size_t)(n0 + 0) * 256 + o] = r0;
        out_g[(size_t)(n0 + 1) * 256 + o] = r1;
        out_g[(size_t)(n0 + 2) * 256 + o] = r2;
        out_g[(size_t)(n0 + 3) * 256 + o] = r3;
    }
}

extern "C" void kernel_launch(void* const* d_in, const int* in_sizes, int n_in,
                              void* d_out, int out_size, void* d_ws, size_t ws_size,
                              hipStream_t stream) {
    (void)in_sizes; (void)n_in; (void)out_size; (void)ws_size;
    const float* ee = (const float*)d_in[0];
    const float* node = (const float*)d_in[1];
    const float* qt = (const float*)d_in[2];
    const float* nkt = (const float*)d_in[3];
    const float* ek = (const float*)d_in[4];
    const float* nvt = (const float*)d_in[5];
    const float* ev = (const float*)d_in[6];
    const float* ot = (const float*)d_in[7];
    float* out = (float*)d_out;

    char* ws = (char*)d_ws;
    u16* qbf = (u16*)(ws);                             // 1 MB  [8][2048][32] bf16
    u16* qebf = (u16*)(ws + (1u << 20));               // 0.5 MB [8][2048][16] bf16
    u16* nk_ws = (u16*)(ws + (1u << 20) + (1u << 19)); // 1 MB  [8][2048][32] bf16
    u16* nvT_ws = (u16*)(ws + (2u << 20) + (1u << 19));// 1 MB [8][32][2048] bf16
    float* accv_ws = (float*)(ws + (3u << 20) + (1u << 19)); // 8 MB [4][8][2048][32]
    float* acce_ws = (float*)(ws + (11u << 20) + (1u << 19));// 4 MB [4][8][2048][16]
    float* ml_ws = (float*)(ws + (15u << 20) + (1u << 19));  // 0.5 MB [4][8][2048][2]

    hipLaunchKernelGGL(k1_precompute, dim3(512), dim3(256), 0, stream,
                       node, qt, nkt, nvt, ek, qbf, qebf, nk_ws, nvT_ws);
    hipLaunchKernelGGL(k2_attn, dim3(512), dim3(512), 0, stream,
                       ee, qbf, qebf, nk_ws, nvT_ws, accv_ws, acce_ws, ml_ws);
    hipLaunchKernelGGL(k3_combine, dim3(512), dim3(256), 0, stream,
                       accv_ws, acce_ws, ml_ws, ev, ot, out);
}